// Round 10
// baseline (160.054 us; speedup 1.0000x reference)
//
#include <hip/hip_runtime.h>

#define KCAP 96u
#define CAP 6144          // cached pos-cell list capacity
#define PBLK 512          // pair_kernel block size
#define NTOT 344064       // 16*(16384+4096+1024)
#define NPAIR 1536
#define CELLS_PB 224      // NTOT / NPAIR exactly

__device__ __forceinline__ float softplus_f(float x) {
    return fmaxf(x, 0.0f) + log1pf(expf(-fabsf(x)));
}

// Exact reproduction of the reference geometry (no fma contraction so we
// match XLA's elementwise fp32 at the selection decision boundaries).
__device__ __forceinline__ void tri_pos_dist(
    float px, float py,
    float ax, float ay, float bx, float by, float cx, float cy,
    bool& pos, float& dist)
{
#pragma clang fp contract(off)
    float d1 = (px - bx) * (ay - by) - (ax - bx) * (py - by);
    float d2 = (px - cx) * (by - cy) - (bx - cx) * (py - cy);
    float d3 = (px - ax) * (cy - ay) - (cx - ax) * (py - ay);
    bool has_neg = (d1 < 0.f) | (d2 < 0.f) | (d3 < 0.f);
    bool has_pos = (d1 > 0.f) | (d2 > 0.f) | (d3 > 0.f);
    bool inside = !(has_neg && has_pos);

    float dAB, dBC, dCA;
    {
        float vx = bx - ax, vy = by - ay, wx = px - ax, wy = py - ay;
        float t = (wx*vx + wy*vy) / (vx*vx + vy*vy + 1e-9f);
        t = fminf(fmaxf(t, 0.0f), 1.0f);
        float dx = px - (ax + t*vx), dy = py - (ay + t*vy);
        dAB = sqrtf(dx*dx + dy*dy + 1e-12f);
    }
    {
        float vx = cx - bx, vy = cy - by, wx = px - bx, wy = py - by;
        float t = (wx*vx + wy*vy) / (vx*vx + vy*vy + 1e-9f);
        t = fminf(fmaxf(t, 0.0f), 1.0f);
        float dx = px - (bx + t*vx), dy = py - (by + t*vy);
        dBC = sqrtf(dx*dx + dy*dy + 1e-12f);
    }
    {
        float vx = ax - cx, vy = ay - cy, wx = px - cx, wy = py - cy;
        float t = (wx*vx + wy*vy) / (vx*vx + vy*vy + 1e-9f);
        t = fminf(fmaxf(t, 0.0f), 1.0f);
        float dx = px - (cx + t*vx), dy = py - (cy + t*vy);
        dCA = sqrtf(dx*dx + dy*dy + 1e-12f);
    }
    dist = fminf(dAB, fminf(dBC, dCA));
    pos = inside || (dist <= 3.0f);
}

// Computes this pair's expanded-bbox candidate-cell count (same arithmetic
// as pair_kernel's bbox; used only as a scheduling key).
__device__ __forceinline__ unsigned bbox_cells(const float* gp, int level) {
    int W; float stride;
    if (level == 0)      { W = 128; stride = 8.0f;  }
    else if (level == 1) { W = 64;  stride = 16.0f; }
    else                 { W = 32;  stride = 32.0f; }
    const float inv = 1.0f / stride;
    float ax = gp[0], ay = gp[1], bx = gp[2], by = gp[3], cx = gp[4], cy = gp[5];
    float minx = fminf(ax, fminf(bx, cx)), maxx = fmaxf(ax, fmaxf(bx, cx));
    float miny = fminf(ay, fminf(by, cy)), maxy = fmaxf(ay, fmaxf(by, cy));
    int wlo = max(0,     (int)floorf((minx - 3.0f) * inv - 0.5f) - 1);
    int whi = min(W - 1, (int)ceilf ((maxx + 3.0f) * inv - 0.5f) + 1);
    int hlo = max(0,     (int)floorf((miny - 3.0f) * inv - 0.5f) - 1);
    int hhi = min(W - 1, (int)ceilf ((maxy + 3.0f) * inv - 0.5f) + 1);
    int ncols = max(0, whi - wlo + 1);
    int nrows = hhi - hlo + 1;
    return (nrows > 0) ? (unsigned)(nrows * ncols) : 0u;
}

// One block, 1024 threads: zero objbits + LPT schedule. Bitonic-sorts the
// 1536 pairs by bbox cell count DESCENDING (2048-wide, padded with 0) and
// writes the dispatch permutation. Largest pairs run first -> small tail.
__global__ __launch_bounds__(1024) void schedule_kernel(
    const float* __restrict__ gt,
    unsigned* __restrict__ objbits,
    unsigned short* __restrict__ perm)
{
    const int t = threadIdx.x;
    for (int i = t; i < 10752; i += 1024) objbits[i] = 0u;

    __shared__ unsigned d[2048];
    #pragma unroll
    for (int s = 0; s < 2; ++s) {
        int i = t + s * 1024;
        unsigned packed = 0u;
        if (i < NPAIR) {
            unsigned nb = bbox_cells(gt + (i & 511) * 6, i >> 9);
            packed = (nb << 11) | (unsigned)i;     // nb<=16384 fits; idx<2048
        }
        d[i] = packed;
    }
    __syncthreads();
    for (unsigned k = 2; k <= 2048u; k <<= 1) {
        for (unsigned j = k >> 1; j > 0; j >>= 1) {
            #pragma unroll
            for (int s = 0; s < 2; ++s) {
                int i = t + s * 1024;
                int ixj = i ^ (int)j;
                if (ixj > i) {
                    unsigned a = d[i], b = d[ixj];
                    bool desc = ((i & k) == 0);    // descending overall
                    if (desc ? (a < b) : (a > b)) { d[i] = b; d[ixj] = a; }
                }
            }
            __syncthreads();
        }
    }
    #pragma unroll
    for (int s = 0; s < 2; ++s) {
        int i = t + s * 1024;
        if (i < NPAIR) perm[i] = (unsigned short)(d[i] & 0x7FFu);
    }
}

// One block (512 threads) per (level, b, g) pair, dispatched via perm (LPT).
// FUSED select + contribute; identical math to round 9 (absmax 0.0):
//  - pass A: one heavy pass over the ETA-expanded bbox (histogram top-11
//    bits + cache (bits,hw) of pos cells in LDS)
//  - exact 32-bit kth refined from cache via two cheap LDS passes; full-bit
//    ties ranked by hw (matches jax.lax.top_k). >CAP: one extra heavy
//    re-cache pass of bin<=T cells; double-overflow -> heavy radix fallback.
//  - contribution consumed directly from the LDS cache; obj union dedup via
//    atomicOr return value (device-coherent, no fence).
//  - rides along: 224 coalesced cells of the global softplus(obj) base sum
//    (chunk indexed by pid so f64 groupings match prior rounds exactly).
__global__ __launch_bounds__(PBLK) void pair_kernel(
    const float* __restrict__ gt,
    const float* __restrict__ reg0, const float* __restrict__ cls0, const float* __restrict__ o0,
    const float* __restrict__ reg1, const float* __restrict__ cls1, const float* __restrict__ o1,
    const float* __restrict__ reg2, const float* __restrict__ cls2, const float* __restrict__ o2,
    const unsigned short* __restrict__ perm,
    unsigned* __restrict__ objbits,
    double* __restrict__ p_reg, double* __restrict__ p_cls,
    double* __restrict__ p_obj, unsigned* __restrict__ p_tc,
    unsigned* __restrict__ p_pos)
{
    const int pid = (int)perm[blockIdx.x];   // scheduled pair id
    const int tid = threadIdx.x;
    const int lane = tid & 63;

    const int level = pid >> 9;        // 512 pairs per level
    const int pair = pid & 511;
    const int b = pair >> 5;

    int W, HW, shift, objbase;
    float stride;
    const float* pr; const float* pcl; const float* po;
    if (level == 0)      { W = 128; HW = 16384; shift = 7; stride = 8.0f;  objbase = 0;     pr = reg0; pcl = cls0; po = o0; }
    else if (level == 1) { W = 64;  HW = 4096;  shift = 6; stride = 16.0f; objbase = 8192;  pr = reg1; pcl = cls1; po = o1; }
    else                 { W = 32;  HW = 1024;  shift = 5; stride = 32.0f; objbase = 10240; pr = reg2; pcl = cls2; po = o2; }
    const int wmask = W - 1;

    // ---- ride-along: global softplus(obj) base sum, 224 coalesced cells ----
    double objAcc = 0.0;
    if (tid < CELLS_PB) {
        int idx = pid * CELLS_PB + tid;
        const float* o; int li;
        if (idx < 262144)      { o = o0; li = idx; }
        else if (idx < 327680) { o = o1; li = idx - 262144; }
        else                   { o = o2; li = idx - 327680; }
        objAcc = (double)softplus_f(o[li]);
    }

    const float* gp = gt + pair * 6;
    const float ax = gp[0], ay = gp[1];
    const float bx = gp[2], by = gp[3];
    const float cx = gp[4], cy = gp[5];

    // ---- expanded bbox of candidate cells (conservative, +1 cell margin) ----
    const float inv = 1.0f / stride;   // power of two: exact
    float minx = fminf(ax, fminf(bx, cx)), maxx = fmaxf(ax, fmaxf(bx, cx));
    float miny = fminf(ay, fminf(by, cy)), maxy = fmaxf(ay, fmaxf(by, cy));
    int wlo = max(0,     (int)floorf((minx - 3.0f) * inv - 0.5f) - 1);
    int whi = min(W - 1, (int)ceilf ((maxx + 3.0f) * inv - 0.5f) + 1);
    int hlo = max(0,     (int)floorf((miny - 3.0f) * inv - 0.5f) - 1);
    int hhi = min(W - 1, (int)ceilf ((maxy + 3.0f) * inv - 0.5f) + 1);
    const int ncols = max(0, whi - wlo + 1);
    const int nb = (hhi - hlo + 1 > 0) ? (hhi - hlo + 1) * ncols : 0;
    const int nbR = (nb + PBLK - 1) & ~(PBLK - 1);
    // magic-multiply division by ncols: exact for i < 2^20, ncols < 2^20
    const unsigned long long dmul =
        (ncols > 0) ? ((1ull << 40) / (unsigned)ncols + 1ull) : 0ull;

    __shared__ unsigned hist[2048];
    __shared__ unsigned chunk[256];
    __shared__ unsigned chunk4[64];
    __shared__ unsigned s_bits[CAP];
    __shared__ unsigned short s_hw[CAP];
    __shared__ unsigned s_cnt, s_T, s_k, s_tiecnt;
    __shared__ double red_reg[8], red_cls[8], red_obj[8];
    __shared__ unsigned red_tc[8], red_pos[8];
    unsigned* tie_hw = hist;   // alias: hist is dead once ties are collected

    if (tid == 0) { s_cnt = 0u; s_tiecnt = 0u; }
    for (int j = tid; j < 2048; j += PBLK) hist[j] = 0u;
    __syncthreads();

    // two-level kth scan: hist -> chunk(256x8) -> chunk4(64x32); out: s_T, s_k
    auto kth_scan = [&](unsigned kk) {
        __syncthreads();
        if (tid < 256) {
            unsigned s = 0; int base = tid * 8;
            #pragma unroll
            for (int j = 0; j < 8; ++j) s += hist[base + j];
            chunk[tid] = s;
        }
        __syncthreads();
        if (tid < 64) {
            int b4 = tid * 4;
            chunk4[tid] = chunk[b4] + chunk[b4+1] + chunk[b4+2] + chunk[b4+3];
        }
        __syncthreads();
        if (tid == 0) {
            unsigned cum = 0; int t4 = 0;
            while (cum + chunk4[t4] < kk) { cum += chunk4[t4]; ++t4; }
            int t = t4 * 4;
            while (cum + chunk[t] < kk) { cum += chunk[t]; ++t; }
            int bb = t * 8;
            while (cum + hist[bb] < kk) { cum += hist[bb]; ++bb; }
            s_T = (unsigned)bb;
            s_k = kk - cum;
        }
        __syncthreads();
    };

    // ---- pass A: single heavy pass; histogram top-11 bits + cache pos cells ----
    for (int i = tid; i < nbR; i += PBLK) {
        bool pos = false; unsigned bits = 0u; int hw = 0;
        if (i < nb) {
            int q = (int)(((unsigned long long)(unsigned)i * dmul) >> 40);
            int w = wlo + (i - q * ncols);
            int h = hlo + q;
            hw = (h << shift) | w;
            float px = (w + 0.5f) * stride;
            float py = (h + 0.5f) * stride;
            float dist;
            tri_pos_dist(px, py, ax, ay, bx, by, cx, cy, pos, dist);
            if (pos) { bits = __float_as_uint(dist); atomicAdd(&hist[bits >> 21], 1u); }
        }
        unsigned long long m = __ballot(pos);
        if (m) {
            int leader = __ffsll(m) - 1;
            unsigned base = 0u;
            if (lane == leader) base = atomicAdd(&s_cnt, (unsigned)__popcll(m));
            base = __shfl(base, leader);
            if (pos) {
                unsigned slot = base + (unsigned)__popcll(m & ((1ull << lane) - 1ull));
                if (slot < CAP) { s_bits[slot] = bits; s_hw[slot] = (unsigned short)hw; }
            }
        }
    }
    __syncthreads();

    const unsigned total = s_cnt;
    const bool fullsel = (total <= KCAP);
    unsigned n = min(total, (unsigned)CAP);
    unsigned kth_bits = 0u, tie_need = 0u;
    bool radix_fb = false;

    if (!fullsel) {
        kth_scan(KCAP);                  // T bin of kth + within-bin rank
        const unsigned T = s_T, kk1 = s_k;

        if (total > CAP) {
            // ---- hybrid: heavy pass 2 re-caches only cells with bin <= T ----
            if (tid == 0) s_cnt = 0u;
            __syncthreads();
            for (int i = tid; i < nbR; i += PBLK) {
                bool keep = false; unsigned bits = 0u; int hw = 0;
                if (i < nb) {
                    int q = (int)(((unsigned long long)(unsigned)i * dmul) >> 40);
                    int w = wlo + (i - q * ncols);
                    int h = hlo + q;
                    hw = (h << shift) | w;
                    float px = (w + 0.5f) * stride;
                    float py = (h + 0.5f) * stride;
                    bool pos; float dist;
                    tri_pos_dist(px, py, ax, ay, bx, by, cx, cy, pos, dist);
                    if (pos) {
                        bits = __float_as_uint(dist);
                        keep = ((bits >> 21) <= T);
                    }
                }
                unsigned long long m = __ballot(keep);
                if (m) {
                    int leader = __ffsll(m) - 1;
                    unsigned base = 0u;
                    if (lane == leader) base = atomicAdd(&s_cnt, (unsigned)__popcll(m));
                    base = __shfl(base, leader);
                    if (keep) {
                        unsigned slot = base + (unsigned)__popcll(m & ((1ull << lane) - 1ull));
                        if (slot < CAP) { s_bits[slot] = bits; s_hw[slot] = (unsigned short)hw; }
                    }
                }
            }
            __syncthreads();
            n = s_cnt;
            if (n > CAP) { radix_fb = true; }
        }

        if (!radix_fb) {
            // ---- exact kth via 2 cheap LDS refinement passes over cache ----
            __syncthreads();
            for (int j = tid; j < 2048; j += PBLK) hist[j] = 0u;
            __syncthreads();
            for (unsigned i = tid; i < n; i += PBLK) {
                unsigned bi = s_bits[i];
                if ((bi >> 21) == T) atomicAdd(&hist[(bi >> 10) & 0x7FFu], 1u);
            }
            kth_scan(kk1);
            unsigned prefix = (T << 11) | s_T;   // top 22 bits
            unsigned kk2 = s_k;
            __syncthreads();
            for (int j = tid; j < 2048; j += PBLK) hist[j] = 0u;
            __syncthreads();
            for (unsigned i = tid; i < n; i += PBLK) {
                unsigned bi = s_bits[i];
                if ((bi >> 10) == prefix) atomicAdd(&hist[bi & 0x3FFu], 1u);
            }
            kth_scan(kk2);
            kth_bits = (prefix << 10) | s_T;     // full 32-bit kth pattern
            tie_need = s_k;
        }
    }

    // ---- contribution (consumed directly from the LDS cache) ----
    double regAcc = 0.0, clsAcc = 0.0;
    unsigned tcAcc = 0u, posAcc = 0u;

    auto contribute = [&](int hw) {
        int h = hw >> shift, w = hw & wmask;
        float px = (w + 0.5f) * stride;
        float py = (h + 0.5f) * stride;
        const float* base = pr + (size_t)b * 6 * HW + hw;
        float p0x = base[0],          p0y = base[HW];
        float p1x = base[2 * HW],     p1y = base[3 * HW];
        float p2x = base[4 * HW],     p2y = base[5 * HW];
        float g0x = (ax - px) * inv,  g0y = (ay - py) * inv;
        float g1x = (bx - px) * inv,  g1y = (by - py) * inv;
        float g2x = (cx - px) * inv,  g2y = (cy - py) * inv;
        float dx0 = p0x - g0x, dy0 = p0y - g0y;
        float p0t = dx0 * dx0 + dy0 * dy0;
        float e11x = p1x - g1x, e11y = p1y - g1y;
        float e12x = p1x - g2x, e12y = p1y - g2y;
        float e21x = p2x - g1x, e21y = p2y - g1y;
        float e22x = p2x - g2x, e22y = p2y - g2y;
        float d11 = sqrtf(e11x * e11x + e11y * e11y);
        float d12 = sqrtf(e12x * e12x + e12y * e12y);
        float d21 = sqrtf(e21x * e21x + e21y * e21y);
        float d22 = sqrtf(e22x * e22x + e22y * e22y);
        float cd = fminf(d11, d12) + fminf(d21, d22) + fminf(d11, d21) + fminf(d12, d22);
        regAcc += (double)(p0t + cd);
        clsAcc += (double)softplus_f(-pcl[(size_t)b * HW + hw]);
        posAcc += 1u;

        unsigned bi = (unsigned)(b * HW + hw);
        unsigned bit = 1u << (bi & 31u);
        unsigned old = atomicOr(&objbits[objbase + (bi >> 5)], bit);
        if (!(old & bit)) {           // first pair to claim this cell
            float x = po[(size_t)b * HW + hw];
            objAcc += (double)(1.2f * softplus_f(-x)) - (double)softplus_f(x);
            tcAcc += 1u;
        }
    };

    if (fullsel) {
        for (unsigned i = tid; i < n; i += PBLK) contribute((int)s_hw[i]);
    } else if (!radix_fb) {
        for (unsigned i = tid; i < n; i += PBLK) {
            unsigned bi = s_bits[i];
            if (bi < kth_bits) {
                contribute((int)s_hw[i]);
            } else if (bi == kth_bits) {
                unsigned t = atomicAdd(&s_tiecnt, 1u);
                if (t < 2048u) tie_hw[t] = s_hw[i];
            }
        }
        __syncthreads();
        unsigned tn = min(s_tiecnt, 2048u);
        for (unsigned i = tid; i < tn; i += PBLK) {
            unsigned hwv = tie_hw[i], rank = 0;
            for (unsigned j = 0; j < tn; ++j) rank += (tie_hw[j] < hwv) ? 1u : 0u;
            if (rank < tie_need) contribute((int)hwv);
        }
    } else {
        // ---- ultra-rare fallback: heavy radix p=1,2 + final heavy pass ----
        unsigned prefix = s_T;   // T from kth_scan(KCAP); s_T/s_k untouched since
        for (int p = 1; p < 3; ++p) {
            unsigned kk = s_k;
            __syncthreads();
            for (int j = tid; j < 2048; j += PBLK) hist[j] = 0u;
            __syncthreads();
            for (int i = tid; i < nb; i += PBLK) {
                int q = (int)(((unsigned long long)(unsigned)i * dmul) >> 40);
                int w = wlo + (i - q * ncols);
                int h = hlo + q;
                float px = (w + 0.5f) * stride;
                float py = (h + 0.5f) * stride;
                bool pos; float dist;
                tri_pos_dist(px, py, ax, ay, bx, by, cx, cy, pos, dist);
                if (!pos) continue;
                unsigned bits = __float_as_uint(dist);
                unsigned bin;
                if (p == 1) { if ((bits >> 21) != prefix) continue; bin = (bits >> 10) & 0x7FFu; }
                else        { if ((bits >> 10) != prefix) continue; bin = bits & 0x3FFu; }
                atomicAdd(&hist[bin], 1u);
            }
            kth_scan(kk);
            prefix = (p == 1) ? ((prefix << 11) | s_T) : ((prefix << 10) | s_T);
        }
        const unsigned kth = prefix, need = s_k;
        for (int i = tid; i < nb; i += PBLK) {
            int q = (int)(((unsigned long long)(unsigned)i * dmul) >> 40);
            int w = wlo + (i - q * ncols);
            int h = hlo + q;
            int hw = (h << shift) | w;
            float px = (w + 0.5f) * stride;
            float py = (h + 0.5f) * stride;
            bool pos; float dist;
            tri_pos_dist(px, py, ax, ay, bx, by, cx, cy, pos, dist);
            if (!pos) continue;
            unsigned bits = __float_as_uint(dist);
            if (bits < kth) {
                contribute(hw);
            } else if (bits == kth) {
                unsigned t = atomicAdd(&s_tiecnt, 1u);
                if (t < 2048u) tie_hw[t] = (unsigned)hw;
            }
        }
        __syncthreads();
        unsigned tn = min(s_tiecnt, 2048u);
        for (unsigned i = tid; i < tn; i += PBLK) {
            unsigned hwv = tie_hw[i], rank = 0;
            for (unsigned j = 0; j < tn; ++j) rank += (tie_hw[j] < hwv) ? 1u : 0u;
            if (rank < need) contribute((int)hwv);
        }
    }

    // ---- block reduce + per-block partial write (original pair slot) ----
    for (int off = 32; off > 0; off >>= 1) {
        regAcc += __shfl_down(regAcc, off);
        clsAcc += __shfl_down(clsAcc, off);
        objAcc += __shfl_down(objAcc, off);
        tcAcc  += __shfl_down(tcAcc, off);
        posAcc += __shfl_down(posAcc, off);
    }
    int wave = tid >> 6;
    if (lane == 0) {
        red_reg[wave] = regAcc; red_cls[wave] = clsAcc; red_obj[wave] = objAcc;
        red_tc[wave] = tcAcc; red_pos[wave] = posAcc;
    }
    __syncthreads();
    if (tid == 0) {
        double rs = 0.0, cs = 0.0, os = 0.0; unsigned ts = 0u, ps = 0u;
        #pragma unroll
        for (int i = 0; i < 8; ++i) {
            rs += red_reg[i]; cs += red_cls[i]; os += red_obj[i];
            ts += red_tc[i]; ps += red_pos[i];
        }
        p_reg[pid] = rs;
        p_cls[pid] = cs;
        p_obj[pid] = os;
        p_tc[pid]  = ts;
        p_pos[pid] = ps;
    }
}

__global__ __launch_bounds__(1024) void finalize_kernel(
    const double* __restrict__ p_reg, const double* __restrict__ p_cls,
    const double* __restrict__ p_obj, const unsigned* __restrict__ p_tc,
    const unsigned* __restrict__ p_pos,
    float* __restrict__ out)
{
    const int tid = threadIdx.x;
    double reg = 0.0, cls = 0.0, obj = 0.0;
    unsigned pc = 0u, tc = 0u;
    for (int i = tid; i < NPAIR; i += 1024) {
        reg += p_reg[i]; cls += p_cls[i]; obj += p_obj[i];
        tc += p_tc[i]; pc += p_pos[i];
    }
    for (int off = 32; off > 0; off >>= 1) {
        reg += __shfl_down(reg, off);
        cls += __shfl_down(cls, off);
        obj += __shfl_down(obj, off);
        pc  += __shfl_down(pc, off);
        tc  += __shfl_down(tc, off);
    }
    __shared__ double rr[16], rc[16], ro[16];
    __shared__ unsigned rp[16], rn[16];
    int wave = tid >> 6, lane = tid & 63;
    if (lane == 0) { rr[wave] = reg; rc[wave] = cls; ro[wave] = obj; rp[wave] = pc; rn[wave] = tc; }
    __syncthreads();
    if (tid == 0) {
        double sreg = 0, scls = 0, sobj = 0; unsigned spc = 0, stc = 0;
        #pragma unroll
        for (int i = 0; i < 16; ++i) {
            sreg += rr[i]; scls += rc[i]; sobj += ro[i]; spc += rp[i]; stc += rn[i];
        }
        double nc = (double)NTOT - (double)stc;
        double pos_eps = fmax((double)spc, 1.0);
        double den = pos_eps + fmax(nc, 1.0);
        out[0] = (float)(sreg / pos_eps + sobj / den + scls / pos_eps);
    }
}

extern "C" void kernel_launch(void* const* d_in, const int* in_sizes, int n_in,
                              void* d_out, int out_size, void* d_ws, size_t ws_size,
                              hipStream_t stream)
{
    (void)in_sizes; (void)n_in; (void)out_size; (void)ws_size;
    const float* reg0 = (const float*)d_in[0];
    const float* obj0 = (const float*)d_in[1];
    const float* cls0 = (const float*)d_in[2];
    const float* reg1 = (const float*)d_in[3];
    const float* obj1 = (const float*)d_in[4];
    const float* cls1 = (const float*)d_in[5];
    const float* reg2 = (const float*)d_in[6];
    const float* obj2 = (const float*)d_in[7];
    const float* cls2 = (const float*)d_in[8];
    const float* gt   = (const float*)d_in[9];

    // ws layout:
    char* ws = (char*)d_ws;
    unsigned*       objbits = (unsigned*)ws;             // u32[10752] [0,      43008)
    double*         p_reg   = (double*)(ws + 43008);     // f64[1536]  [43008,  55296)
    double*         p_cls   = (double*)(ws + 55296);     // f64[1536]  [55296,  67584)
    double*         p_obj   = (double*)(ws + 67584);     // f64[1536]  [67584,  79872)
    unsigned*       p_tc    = (unsigned*)(ws + 79872);   // u32[1536]  [79872,  86016)
    unsigned*       p_pos   = (unsigned*)(ws + 86016);   // u32[1536]  [86016,  92160)
    unsigned short* perm    = (unsigned short*)(ws + 92160); // u16[1536] [92160, 95232)

    schedule_kernel<<<1, 1024, 0, stream>>>(gt, objbits, perm);
    pair_kernel<<<NPAIR, PBLK, 0, stream>>>(gt,
                                            reg0, cls0, obj0,
                                            reg1, cls1, obj1,
                                            reg2, cls2, obj2,
                                            perm, objbits,
                                            p_reg, p_cls, p_obj, p_tc, p_pos);
    finalize_kernel<<<1, 1024, 0, stream>>>(p_reg, p_cls, p_obj, p_tc, p_pos,
                                            (float*)d_out);
}

// Round 11
// 138.656 us; speedup vs baseline: 1.1543x; 1.1543x over previous
//
#include <hip/hip_runtime.h>

#define KCAP 96u
#define CAP 6144          // cached pos-cell list capacity
#define PBLK 512          // pair_kernel block size
#define NTOT 344064       // 16*(16384+4096+1024)
#define NPAIR 1536
#define CELLS_PB 224      // NTOT / NPAIR exactly

__device__ __forceinline__ float softplus_f(float x) {
    return fmaxf(x, 0.0f) + log1pf(expf(-fabsf(x)));
}

// Exact reproduction of the reference geometry (no fma contraction so we
// match XLA's elementwise fp32 at the selection decision boundaries).
__device__ __forceinline__ void tri_pos_dist(
    float px, float py,
    float ax, float ay, float bx, float by, float cx, float cy,
    bool& pos, float& dist)
{
#pragma clang fp contract(off)
    float d1 = (px - bx) * (ay - by) - (ax - bx) * (py - by);
    float d2 = (px - cx) * (by - cy) - (bx - cx) * (py - cy);
    float d3 = (px - ax) * (cy - ay) - (cx - ax) * (py - ay);
    bool has_neg = (d1 < 0.f) | (d2 < 0.f) | (d3 < 0.f);
    bool has_pos = (d1 > 0.f) | (d2 > 0.f) | (d3 > 0.f);
    bool inside = !(has_neg && has_pos);

    float dAB, dBC, dCA;
    {
        float vx = bx - ax, vy = by - ay, wx = px - ax, wy = py - ay;
        float t = (wx*vx + wy*vy) / (vx*vx + vy*vy + 1e-9f);
        t = fminf(fmaxf(t, 0.0f), 1.0f);
        float dx = px - (ax + t*vx), dy = py - (ay + t*vy);
        dAB = sqrtf(dx*dx + dy*dy + 1e-12f);
    }
    {
        float vx = cx - bx, vy = cy - by, wx = px - bx, wy = py - by;
        float t = (wx*vx + wy*vy) / (vx*vx + vy*vy + 1e-9f);
        t = fminf(fmaxf(t, 0.0f), 1.0f);
        float dx = px - (bx + t*vx), dy = py - (by + t*vy);
        dBC = sqrtf(dx*dx + dy*dy + 1e-12f);
    }
    {
        float vx = ax - cx, vy = ay - cy, wx = px - cx, wy = py - cy;
        float t = (wx*vx + wy*vy) / (vx*vx + vy*vy + 1e-9f);
        t = fminf(fmaxf(t, 0.0f), 1.0f);
        float dx = px - (cx + t*vx), dy = py - (cy + t*vy);
        dCA = sqrtf(dx*dx + dy*dy + 1e-12f);
    }
    dist = fminf(dAB, fminf(dBC, dCA));
    pos = inside || (dist <= 3.0f);
}

// One block, 1024 threads: zero objbits + cheap LPT bucket schedule.
// Key = estimated candidate cells (halfplane-trimmed area model), bucketed
// into 128 levels; descending-bucket counting sort (order within bucket
// arbitrary). ~4 barriers vs bitonic's 66.
__global__ __launch_bounds__(1024) void schedule_kernel(
    const float* __restrict__ gt,
    unsigned* __restrict__ objbits,
    unsigned short* __restrict__ perm)
{
    const int t = threadIdx.x;
    for (int i = t; i < 10752; i += 1024) objbits[i] = 0u;

    __shared__ unsigned cnt[128];
    __shared__ unsigned start[128];
    if (t < 128) cnt[t] = 0u;
    __syncthreads();

    unsigned bkt[2] = {0u, 0u};
    #pragma unroll
    for (int s = 0; s < 2; ++s) {
        int i = t + s * 1024;
        if (i < NPAIR) {
            const float* gp = gt + (i & 511) * 6;
            float ax = gp[0], ay = gp[1], bx = gp[2], by = gp[3], cx = gp[4], cy = gp[5];
            float stride = (i >> 9) == 0 ? 8.0f : ((i >> 9) == 1 ? 16.0f : 32.0f);
            float inv = 1.0f / stride;
            float area2 = fabsf((bx - ax) * (cy - ay) - (cx - ax) * (by - ay));
            float l1 = sqrtf((ax-bx)*(ax-bx) + (ay-by)*(ay-by));
            float l2 = sqrtf((bx-cx)*(bx-cx) + (by-cy)*(by-cy));
            float l3 = sqrtf((cx-ax)*(cx-ax) + (cy-ay)*(cy-ay));
            float est = 0.5f * area2 * inv * inv + 3.05f * inv * (l1 + l2 + l3) + 40.0f;
            unsigned b = min(127u, (unsigned)est >> 7);
            bkt[s] = b;
            atomicAdd(&cnt[b], 1u);
        }
    }
    __syncthreads();
    if (t == 0) {
        unsigned acc = 0u;
        for (int b = 127; b >= 0; --b) { start[b] = acc; acc += cnt[b]; }
    }
    __syncthreads();
    if (t < 128) cnt[t] = 0u;   // reuse as per-bucket cursor
    __syncthreads();
    #pragma unroll
    for (int s = 0; s < 2; ++s) {
        int i = t + s * 1024;
        if (i < NPAIR) {
            unsigned slot = start[bkt[s]] + atomicAdd(&cnt[bkt[s]], 1u);
            perm[slot] = (unsigned short)i;
        }
    }
}

// One block (512 threads) per pair, dispatched via perm (LPT). FUSED
// select + contribute, with the candidate set trimmed per-row by the three
// expanded half-plane constraints: any pos cell p satisfies
// s*d_e(p) >= -3*len_e for ALL edges (cross is len_e-Lipschitz; boundary
// points have s*d_e >= 0). Margin 3.05 + 1-cell safety keeps it strictly
// conservative; the exact pos test decides, so selection is bit-identical.
__global__ __launch_bounds__(PBLK) void pair_kernel(
    const float* __restrict__ gt,
    const float* __restrict__ reg0, const float* __restrict__ cls0, const float* __restrict__ o0,
    const float* __restrict__ reg1, const float* __restrict__ cls1, const float* __restrict__ o1,
    const float* __restrict__ reg2, const float* __restrict__ cls2, const float* __restrict__ o2,
    const unsigned short* __restrict__ perm,
    unsigned* __restrict__ objbits,
    double* __restrict__ p_reg, double* __restrict__ p_cls,
    double* __restrict__ p_obj, unsigned* __restrict__ p_tc,
    unsigned* __restrict__ p_pos)
{
    const int pid = (int)perm[blockIdx.x];   // scheduled pair id
    const int tid = threadIdx.x;
    const int lane = tid & 63;

    const int level = pid >> 9;        // 512 pairs per level
    const int pair = pid & 511;
    const int b = pair >> 5;

    int W, HW, shift, objbase;
    float stride;
    const float* pr; const float* pcl; const float* po;
    if (level == 0)      { W = 128; HW = 16384; shift = 7; stride = 8.0f;  objbase = 0;     pr = reg0; pcl = cls0; po = o0; }
    else if (level == 1) { W = 64;  HW = 4096;  shift = 6; stride = 16.0f; objbase = 8192;  pr = reg1; pcl = cls1; po = o1; }
    else                 { W = 32;  HW = 1024;  shift = 5; stride = 32.0f; objbase = 10240; pr = reg2; pcl = cls2; po = o2; }
    const int wmask = W - 1;

    // ---- ride-along: global softplus(obj) base sum, 224 coalesced cells ----
    double objAcc = 0.0;
    if (tid < CELLS_PB) {
        int idx = pid * CELLS_PB + tid;
        const float* o; int li;
        if (idx < 262144)      { o = o0; li = idx; }
        else if (idx < 327680) { o = o1; li = idx - 262144; }
        else                   { o = o2; li = idx - 327680; }
        objAcc = (double)softplus_f(o[li]);
    }

    const float* gp = gt + pair * 6;
    const float ax = gp[0], ay = gp[1];
    const float bx = gp[2], by = gp[3];
    const float cx = gp[4], cy = gp[5];

    // ---- expanded bbox (conservative, +1 cell margin) ----
    const float inv = 1.0f / stride;   // power of two: exact
    float minx = fminf(ax, fminf(bx, cx)), maxx = fmaxf(ax, fmaxf(bx, cx));
    float miny = fminf(ay, fminf(by, cy)), maxy = fmaxf(ay, fmaxf(by, cy));
    int wlo = max(0,     (int)floorf((minx - 3.0f) * inv - 0.5f) - 1);
    int whi = min(W - 1, (int)ceilf ((maxx + 3.0f) * inv - 0.5f) + 1);
    int hlo = max(0,     (int)floorf((miny - 3.0f) * inv - 0.5f) - 1);
    int hhi = min(W - 1, (int)ceilf ((maxy + 3.0f) * inv - 0.5f) + 1);
    const int nrows = max(0, hhi - hlo + 1);   // <= 128

    // ---- half-plane trim setup (block-uniform) ----
    float area2 = (bx - ax) * (cy - ay) - (cx - ax) * (by - ay);
    const float sgnf = (area2 > 0.f) ? 1.f : ((area2 < 0.f) ? -1.f : 0.f);
    const float a1 = ay - by, a2 = by - cy, a3 = cy - ay;
    const float T1 = 3.05f * sqrtf((ax-bx)*(ax-bx) + (ay-by)*(ay-by));
    const float T2 = 3.05f * sqrtf((bx-cx)*(bx-cx) + (by-cy)*(by-cy));
    const float T3 = 3.05f * sqrtf((cx-ax)*(cx-ax) + (cy-ay)*(cy-ay));

    __shared__ unsigned hist[2048];
    __shared__ unsigned chunk[256];
    __shared__ unsigned chunk4[64];
    __shared__ unsigned s_bits[CAP];
    __shared__ unsigned short s_hw[CAP];
    __shared__ short s_rowlo[128];
    __shared__ unsigned s_rowstart[129];
    __shared__ unsigned s_cnt, s_T, s_k, s_tiecnt;
    __shared__ double red_reg[8], red_cls[8], red_obj[8];
    __shared__ unsigned red_tc[8], red_pos[8];
    unsigned* tie_hw = hist;   // alias: hist is dead once ties are collected

    if (tid == 0) { s_cnt = 0u; s_tiecnt = 0u; s_rowstart[0] = 0u; }
    for (int j = tid; j < 2048; j += PBLK) hist[j] = 0u;

    // ---- per-row column interval from the 3 expanded half-planes ----
    if (tid < nrows) {
        float py = ((hlo + tid) + 0.5f) * stride;
        int wl = wlo, wh = whi;
        if (sgnf != 0.f) {
            float xlo = minx - 3.0f - stride;
            float xhi = maxx + 3.0f + stride;
            bool ok = true;
            float c1 = -bx * a1 - (ax - bx) * (py - by);
            float c2 = -cx * a2 - (bx - cx) * (py - cy);
            float c3 = -ax * a3 - (cx - ax) * (py - ay);
            float ap, cp;
            ap = sgnf * a1; cp = sgnf * c1;
            if (ap > 0.f)      xlo = fmaxf(xlo, (-T1 - cp) / ap);
            else if (ap < 0.f) xhi = fminf(xhi, (-T1 - cp) / ap);
            else if (cp < -T1) ok = false;
            ap = sgnf * a2; cp = sgnf * c2;
            if (ap > 0.f)      xlo = fmaxf(xlo, (-T2 - cp) / ap);
            else if (ap < 0.f) xhi = fminf(xhi, (-T2 - cp) / ap);
            else if (cp < -T2) ok = false;
            ap = sgnf * a3; cp = sgnf * c3;
            if (ap > 0.f)      xlo = fmaxf(xlo, (-T3 - cp) / ap);
            else if (ap < 0.f) xhi = fminf(xhi, (-T3 - cp) / ap);
            else if (cp < -T3) ok = false;
            if (ok) {
                wl = max(wlo, (int)floorf(xlo * inv - 0.5f) - 1);
                wh = min(whi, (int)ceilf (xhi * inv - 0.5f) + 1);
            } else { wl = 1; wh = 0; }
        }
        s_rowlo[tid] = (short)wl;
        s_rowstart[tid + 1] = (wh >= wl) ? (unsigned)(wh - wl + 1) : 0u;
    }
    __syncthreads();
    if (tid == 0)
        for (int r = 0; r < nrows; ++r) s_rowstart[r + 1] += s_rowstart[r];
    __syncthreads();

    const int M  = (nrows > 0) ? (int)s_rowstart[nrows] : 0;
    const int MR = (M + PBLK - 1) & ~(PBLK - 1);

    // flat candidate index -> (hw, px, py) via binary search in row prefix
    auto map_cell = [&](int j, int& hw, float& px, float& py) {
        int lo = 0, hi = nrows - 1;
        while (lo < hi) {
            int mid = (lo + hi + 1) >> 1;
            if (s_rowstart[mid] <= (unsigned)j) lo = mid; else hi = mid - 1;
        }
        int w = (int)s_rowlo[lo] + (j - (int)s_rowstart[lo]);
        int h = hlo + lo;
        hw = (h << shift) | w;
        px = (w + 0.5f) * stride;
        py = (h + 0.5f) * stride;
    };

    // two-level kth scan: hist -> chunk(256x8) -> chunk4(64x32); out: s_T, s_k
    auto kth_scan = [&](unsigned kk) {
        __syncthreads();
        if (tid < 256) {
            unsigned s = 0; int base = tid * 8;
            #pragma unroll
            for (int j = 0; j < 8; ++j) s += hist[base + j];
            chunk[tid] = s;
        }
        __syncthreads();
        if (tid < 64) {
            int b4 = tid * 4;
            chunk4[tid] = chunk[b4] + chunk[b4+1] + chunk[b4+2] + chunk[b4+3];
        }
        __syncthreads();
        if (tid == 0) {
            unsigned cum = 0; int t4 = 0;
            while (cum + chunk4[t4] < kk) { cum += chunk4[t4]; ++t4; }
            int t = t4 * 4;
            while (cum + chunk[t] < kk) { cum += chunk[t]; ++t; }
            int bb = t * 8;
            while (cum + hist[bb] < kk) { cum += hist[bb]; ++bb; }
            s_T = (unsigned)bb;
            s_k = kk - cum;
        }
        __syncthreads();
    };

    // ---- pass A: single heavy pass over trimmed set; histogram + cache ----
    for (int i = tid; i < MR; i += PBLK) {
        bool pos = false; unsigned bits = 0u; int hw = 0;
        if (i < M) {
            float px, py;
            map_cell(i, hw, px, py);
            float dist;
            tri_pos_dist(px, py, ax, ay, bx, by, cx, cy, pos, dist);
            if (pos) { bits = __float_as_uint(dist); atomicAdd(&hist[bits >> 21], 1u); }
        }
        unsigned long long m = __ballot(pos);
        if (m) {
            int leader = __ffsll(m) - 1;
            unsigned base = 0u;
            if (lane == leader) base = atomicAdd(&s_cnt, (unsigned)__popcll(m));
            base = __shfl(base, leader);
            if (pos) {
                unsigned slot = base + (unsigned)__popcll(m & ((1ull << lane) - 1ull));
                if (slot < CAP) { s_bits[slot] = bits; s_hw[slot] = (unsigned short)hw; }
            }
        }
    }
    __syncthreads();

    const unsigned total = s_cnt;
    const bool fullsel = (total <= KCAP);
    unsigned n = min(total, (unsigned)CAP);
    unsigned kth_bits = 0u, tie_need = 0u;
    bool radix_fb = false;

    if (!fullsel) {
        kth_scan(KCAP);                  // T bin of kth + within-bin rank
        const unsigned T = s_T, kk1 = s_k;

        if (total > CAP) {
            // ---- hybrid: heavy pass 2 re-caches only cells with bin <= T ----
            if (tid == 0) s_cnt = 0u;
            __syncthreads();
            for (int i = tid; i < MR; i += PBLK) {
                bool keep = false; unsigned bits = 0u; int hw = 0;
                if (i < M) {
                    float px, py;
                    map_cell(i, hw, px, py);
                    bool pos; float dist;
                    tri_pos_dist(px, py, ax, ay, bx, by, cx, cy, pos, dist);
                    if (pos) {
                        bits = __float_as_uint(dist);
                        keep = ((bits >> 21) <= T);
                    }
                }
                unsigned long long m = __ballot(keep);
                if (m) {
                    int leader = __ffsll(m) - 1;
                    unsigned base = 0u;
                    if (lane == leader) base = atomicAdd(&s_cnt, (unsigned)__popcll(m));
                    base = __shfl(base, leader);
                    if (keep) {
                        unsigned slot = base + (unsigned)__popcll(m & ((1ull << lane) - 1ull));
                        if (slot < CAP) { s_bits[slot] = bits; s_hw[slot] = (unsigned short)hw; }
                    }
                }
            }
            __syncthreads();
            n = s_cnt;
            if (n > CAP) { radix_fb = true; }
        }

        if (!radix_fb) {
            // ---- exact kth via 2 cheap LDS refinement passes over cache ----
            __syncthreads();
            for (int j = tid; j < 2048; j += PBLK) hist[j] = 0u;
            __syncthreads();
            for (unsigned i = tid; i < n; i += PBLK) {
                unsigned bi = s_bits[i];
                if ((bi >> 21) == T) atomicAdd(&hist[(bi >> 10) & 0x7FFu], 1u);
            }
            kth_scan(kk1);
            unsigned prefix = (T << 11) | s_T;   // top 22 bits
            unsigned kk2 = s_k;
            __syncthreads();
            for (int j = tid; j < 2048; j += PBLK) hist[j] = 0u;
            __syncthreads();
            for (unsigned i = tid; i < n; i += PBLK) {
                unsigned bi = s_bits[i];
                if ((bi >> 10) == prefix) atomicAdd(&hist[bi & 0x3FFu], 1u);
            }
            kth_scan(kk2);
            kth_bits = (prefix << 10) | s_T;     // full 32-bit kth pattern
            tie_need = s_k;
        }
    }

    // ---- contribution (consumed directly from the LDS cache) ----
    double regAcc = 0.0, clsAcc = 0.0;
    unsigned tcAcc = 0u, posAcc = 0u;

    auto contribute = [&](int hw) {
        int h = hw >> shift, w = hw & wmask;
        float px = (w + 0.5f) * stride;
        float py = (h + 0.5f) * stride;
        const float* base = pr + (size_t)b * 6 * HW + hw;
        float p0x = base[0],          p0y = base[HW];
        float p1x = base[2 * HW],     p1y = base[3 * HW];
        float p2x = base[4 * HW],     p2y = base[5 * HW];
        float g0x = (ax - px) * inv,  g0y = (ay - py) * inv;
        float g1x = (bx - px) * inv,  g1y = (by - py) * inv;
        float g2x = (cx - px) * inv,  g2y = (cy - py) * inv;
        float dx0 = p0x - g0x, dy0 = p0y - g0y;
        float p0t = dx0 * dx0 + dy0 * dy0;
        float e11x = p1x - g1x, e11y = p1y - g1y;
        float e12x = p1x - g2x, e12y = p1y - g2y;
        float e21x = p2x - g1x, e21y = p2y - g1y;
        float e22x = p2x - g2x, e22y = p2y - g2y;
        float d11 = sqrtf(e11x * e11x + e11y * e11y);
        float d12 = sqrtf(e12x * e12x + e12y * e12y);
        float d21 = sqrtf(e21x * e21x + e21y * e21y);
        float d22 = sqrtf(e22x * e22x + e22y * e22y);
        float cd = fminf(d11, d12) + fminf(d21, d22) + fminf(d11, d21) + fminf(d12, d22);
        regAcc += (double)(p0t + cd);
        clsAcc += (double)softplus_f(-pcl[(size_t)b * HW + hw]);
        posAcc += 1u;

        unsigned bi = (unsigned)(b * HW + hw);
        unsigned bit = 1u << (bi & 31u);
        unsigned old = atomicOr(&objbits[objbase + (bi >> 5)], bit);
        if (!(old & bit)) {           // first pair to claim this cell
            float x = po[(size_t)b * HW + hw];
            objAcc += (double)(1.2f * softplus_f(-x)) - (double)softplus_f(x);
            tcAcc += 1u;
        }
    };

    if (fullsel) {
        for (unsigned i = tid; i < n; i += PBLK) contribute((int)s_hw[i]);
    } else if (!radix_fb) {
        for (unsigned i = tid; i < n; i += PBLK) {
            unsigned bi = s_bits[i];
            if (bi < kth_bits) {
                contribute((int)s_hw[i]);
            } else if (bi == kth_bits) {
                unsigned t = atomicAdd(&s_tiecnt, 1u);
                if (t < 2048u) tie_hw[t] = s_hw[i];
            }
        }
        __syncthreads();
        unsigned tn = min(s_tiecnt, 2048u);
        for (unsigned i = tid; i < tn; i += PBLK) {
            unsigned hwv = tie_hw[i], rank = 0;
            for (unsigned j = 0; j < tn; ++j) rank += (tie_hw[j] < hwv) ? 1u : 0u;
            if (rank < tie_need) contribute((int)hwv);
        }
    } else {
        // ---- ultra-rare fallback: heavy radix p=1,2 + final heavy pass ----
        unsigned prefix = s_T;   // T from kth_scan(KCAP); s_T/s_k untouched since
        for (int p = 1; p < 3; ++p) {
            unsigned kk = s_k;
            __syncthreads();
            for (int j = tid; j < 2048; j += PBLK) hist[j] = 0u;
            __syncthreads();
            for (int i = tid; i < M; i += PBLK) {
                int hw; float px, py;
                map_cell(i, hw, px, py);
                bool pos; float dist;
                tri_pos_dist(px, py, ax, ay, bx, by, cx, cy, pos, dist);
                if (!pos) continue;
                unsigned bits = __float_as_uint(dist);
                unsigned bin;
                if (p == 1) { if ((bits >> 21) != prefix) continue; bin = (bits >> 10) & 0x7FFu; }
                else        { if ((bits >> 10) != prefix) continue; bin = bits & 0x3FFu; }
                atomicAdd(&hist[bin], 1u);
            }
            kth_scan(kk);
            prefix = (p == 1) ? ((prefix << 11) | s_T) : ((prefix << 10) | s_T);
        }
        const unsigned kth = prefix, need = s_k;
        for (int i = tid; i < M; i += PBLK) {
            int hw; float px, py;
            map_cell(i, hw, px, py);
            bool pos; float dist;
            tri_pos_dist(px, py, ax, ay, bx, by, cx, cy, pos, dist);
            if (!pos) continue;
            unsigned bits = __float_as_uint(dist);
            if (bits < kth) {
                contribute(hw);
            } else if (bits == kth) {
                unsigned t = atomicAdd(&s_tiecnt, 1u);
                if (t < 2048u) tie_hw[t] = (unsigned)hw;
            }
        }
        __syncthreads();
        unsigned tn = min(s_tiecnt, 2048u);
        for (unsigned i = tid; i < tn; i += PBLK) {
            unsigned hwv = tie_hw[i], rank = 0;
            for (unsigned j = 0; j < tn; ++j) rank += (tie_hw[j] < hwv) ? 1u : 0u;
            if (rank < need) contribute((int)hwv);
        }
    }

    // ---- block reduce + per-block partial write (original pair slot) ----
    for (int off = 32; off > 0; off >>= 1) {
        regAcc += __shfl_down(regAcc, off);
        clsAcc += __shfl_down(clsAcc, off);
        objAcc += __shfl_down(objAcc, off);
        tcAcc  += __shfl_down(tcAcc, off);
        posAcc += __shfl_down(posAcc, off);
    }
    int wave = tid >> 6;
    if (lane == 0) {
        red_reg[wave] = regAcc; red_cls[wave] = clsAcc; red_obj[wave] = objAcc;
        red_tc[wave] = tcAcc; red_pos[wave] = posAcc;
    }
    __syncthreads();
    if (tid == 0) {
        double rs = 0.0, cs = 0.0, os = 0.0; unsigned ts = 0u, ps = 0u;
        #pragma unroll
        for (int i = 0; i < 8; ++i) {
            rs += red_reg[i]; cs += red_cls[i]; os += red_obj[i];
            ts += red_tc[i]; ps += red_pos[i];
        }
        p_reg[pid] = rs;
        p_cls[pid] = cs;
        p_obj[pid] = os;
        p_tc[pid]  = ts;
        p_pos[pid] = ps;
    }
}

__global__ __launch_bounds__(1024) void finalize_kernel(
    const double* __restrict__ p_reg, const double* __restrict__ p_cls,
    const double* __restrict__ p_obj, const unsigned* __restrict__ p_tc,
    const unsigned* __restrict__ p_pos,
    float* __restrict__ out)
{
    const int tid = threadIdx.x;
    double reg = 0.0, cls = 0.0, obj = 0.0;
    unsigned pc = 0u, tc = 0u;
    for (int i = tid; i < NPAIR; i += 1024) {
        reg += p_reg[i]; cls += p_cls[i]; obj += p_obj[i];
        tc += p_tc[i]; pc += p_pos[i];
    }
    for (int off = 32; off > 0; off >>= 1) {
        reg += __shfl_down(reg, off);
        cls += __shfl_down(cls, off);
        obj += __shfl_down(obj, off);
        pc  += __shfl_down(pc, off);
        tc  += __shfl_down(tc, off);
    }
    __shared__ double rr[16], rc[16], ro[16];
    __shared__ unsigned rp[16], rn[16];
    int wave = tid >> 6, lane = tid & 63;
    if (lane == 0) { rr[wave] = reg; rc[wave] = cls; ro[wave] = obj; rp[wave] = pc; rn[wave] = tc; }
    __syncthreads();
    if (tid == 0) {
        double sreg = 0, scls = 0, sobj = 0; unsigned spc = 0, stc = 0;
        #pragma unroll
        for (int i = 0; i < 16; ++i) {
            sreg += rr[i]; scls += rc[i]; sobj += ro[i]; spc += rp[i]; stc += rn[i];
        }
        double nc = (double)NTOT - (double)stc;
        double pos_eps = fmax((double)spc, 1.0);
        double den = pos_eps + fmax(nc, 1.0);
        out[0] = (float)(sreg / pos_eps + sobj / den + scls / pos_eps);
    }
}

extern "C" void kernel_launch(void* const* d_in, const int* in_sizes, int n_in,
                              void* d_out, int out_size, void* d_ws, size_t ws_size,
                              hipStream_t stream)
{
    (void)in_sizes; (void)n_in; (void)out_size; (void)ws_size;
    const float* reg0 = (const float*)d_in[0];
    const float* obj0 = (const float*)d_in[1];
    const float* cls0 = (const float*)d_in[2];
    const float* reg1 = (const float*)d_in[3];
    const float* obj1 = (const float*)d_in[4];
    const float* cls1 = (const float*)d_in[5];
    const float* reg2 = (const float*)d_in[6];
    const float* obj2 = (const float*)d_in[7];
    const float* cls2 = (const float*)d_in[8];
    const float* gt   = (const float*)d_in[9];

    // ws layout:
    char* ws = (char*)d_ws;
    unsigned*       objbits = (unsigned*)ws;             // u32[10752] [0,      43008)
    double*         p_reg   = (double*)(ws + 43008);     // f64[1536]  [43008,  55296)
    double*         p_cls   = (double*)(ws + 55296);     // f64[1536]  [55296,  67584)
    double*         p_obj   = (double*)(ws + 67584);     // f64[1536]  [67584,  79872)
    unsigned*       p_tc    = (unsigned*)(ws + 79872);   // u32[1536]  [79872,  86016)
    unsigned*       p_pos   = (unsigned*)(ws + 86016);   // u32[1536]  [86016,  92160)
    unsigned short* perm    = (unsigned short*)(ws + 92160); // u16[1536] [92160, 95232)

    schedule_kernel<<<1, 1024, 0, stream>>>(gt, objbits, perm);
    pair_kernel<<<NPAIR, PBLK, 0, stream>>>(gt,
                                            reg0, cls0, obj0,
                                            reg1, cls1, obj1,
                                            reg2, cls2, obj2,
                                            perm, objbits,
                                            p_reg, p_cls, p_obj, p_tc, p_pos);
    finalize_kernel<<<1, 1024, 0, stream>>>(p_reg, p_cls, p_obj, p_tc, p_pos,
                                            (float*)d_out);
}